// Round 1
// baseline (254.435 us; speedup 1.0000x reference)
//
#include <hip/hip_runtime.h>

// Trilinear interpolation of a 128^3 x 16 latent grid at 2M points.
// 4 lanes per point; lane owns one float4 of the 16-dim feature vector.

constexpr int GRID_RES = 128;
constexpr int LATENT_DIM = 16;

__global__ __launch_bounds__(256) void trilerp_kernel(
    const float* __restrict__ pts,      // [N,3]
    const float* __restrict__ latents,  // [R^3, 16]
    float* __restrict__ out,            // [N,16]
    int n_pts)
{
    const int tid = blockIdx.x * blockDim.x + threadIdx.x;
    const int p = tid >> 2;       // point index
    const int q = tid & 3;        // which float4 of the 16 features
    if (p >= n_pts) return;

    const float px = pts[p * 3 + 0];
    const float py = pts[p * 3 + 1];
    const float pz = pts[p * 3 + 2];

    const float S = (float)(GRID_RES - 2);   // 126
    const float sx = px * S, sy = py * S, sz = pz * S;
    const float bx = floorf(sx), by = floorf(sy), bz = floorf(sz);
    const int ix = (int)bx, iy = (int)by, iz = (int)bz;

    const float wbx = sx - bx, wby = sy - by, wbz = sz - bz;
    const float wax = 1.0f - wbx, way = 1.0f - wby, waz = 1.0f - wbz;

    // clamped corner coords
    const int x0 = min(max(ix,     0), GRID_RES - 1);
    const int x1 = min(max(ix + 1, 0), GRID_RES - 1);
    const int y0 = min(max(iy,     0), GRID_RES - 1);
    const int y1 = min(max(iy + 1, 0), GRID_RES - 1);
    const int z0 = min(max(iz,     0), GRID_RES - 1);
    const int z1 = min(max(iz + 1, 0), GRID_RES - 1);

    const int cx[2] = {x0, x1};
    const int cy[2] = {y0, y1};
    const int cz[2] = {z0, z1};
    const float fx[2] = {wax, wbx};
    const float fy[2] = {way, wby};
    const float fz[2] = {waz, wbz};

    float4 acc = make_float4(0.f, 0.f, 0.f, 0.f);

    // corner order matches reference _OFFSETS: (x,y,z) = 000,001,010,011,100,...
    #pragma unroll
    for (int ox = 0; ox < 2; ++ox) {
        #pragma unroll
        for (int oy = 0; oy < 2; ++oy) {
            #pragma unroll
            for (int oz = 0; oz < 2; ++oz) {
                const int flat = cx[ox] * (GRID_RES * GRID_RES)
                               + cy[oy] * GRID_RES + cz[oz];
                const float w = fx[ox] * fy[oy] * fz[oz];
                const float4 f = *reinterpret_cast<const float4*>(
                    latents + (size_t)flat * LATENT_DIM + q * 4);
                acc.x += w * f.x;
                acc.y += w * f.y;
                acc.z += w * f.z;
                acc.w += w * f.w;
            }
        }
    }

    *reinterpret_cast<float4*>(out + (size_t)p * LATENT_DIM + q * 4) = acc;
}

extern "C" void kernel_launch(void* const* d_in, const int* in_sizes, int n_in,
                              void* d_out, int out_size, void* d_ws, size_t ws_size,
                              hipStream_t stream) {
    const float* pts     = (const float*)d_in[0];
    const float* latents = (const float*)d_in[1];
    float* out = (float*)d_out;

    const int n_pts = in_sizes[0] / 3;
    const int total_threads = n_pts * 4;
    const int block = 256;
    const int grid = (total_threads + block - 1) / block;

    trilerp_kernel<<<grid, block, 0, stream>>>(pts, latents, out, n_pts);
}

// Round 3
// 252.858 us; speedup vs baseline: 1.0062x; 1.0062x over previous
//
#include <hip/hip_runtime.h>

// Trilinear interpolation of a 128^3 x 16 latent grid at 2M points.
// 4 lanes per point; lane owns one float4 of the 16-dim feature vector.
// Streaming traffic (pts reads, out writes) is non-temporal so the 256 MiB
// Infinity Cache keeps the 134 MB latent table resident and absorbs the
// random gather re-reads.

constexpr int GRID_RES = 128;
constexpr int LATENT_DIM = 16;

typedef float fvec4 __attribute__((ext_vector_type(4)));  // native vector for NT builtins

__global__ __launch_bounds__(256) void trilerp_kernel(
    const float* __restrict__ pts,      // [N,3]
    const float* __restrict__ latents,  // [R^3, 16]
    float* __restrict__ out,            // [N,16]
    int n_pts)
{
    const int tid = blockIdx.x * blockDim.x + threadIdx.x;
    const int p = tid >> 2;       // point index
    const int q = tid & 3;        // which float4 of the 16 features
    if (p >= n_pts) return;

    const float px = __builtin_nontemporal_load(pts + p * 3 + 0);
    const float py = __builtin_nontemporal_load(pts + p * 3 + 1);
    const float pz = __builtin_nontemporal_load(pts + p * 3 + 2);

    const float S = (float)(GRID_RES - 2);   // 126
    const float sx = px * S, sy = py * S, sz = pz * S;
    const float bx = floorf(sx), by = floorf(sy), bz = floorf(sz);
    const int ix = (int)bx, iy = (int)by, iz = (int)bz;

    const float wbx = sx - bx, wby = sy - by, wbz = sz - bz;
    const float wax = 1.0f - wbx, way = 1.0f - wby, waz = 1.0f - wbz;

    // clamped corner coords
    const int x0 = min(max(ix,     0), GRID_RES - 1);
    const int x1 = min(max(ix + 1, 0), GRID_RES - 1);
    const int y0 = min(max(iy,     0), GRID_RES - 1);
    const int y1 = min(max(iy + 1, 0), GRID_RES - 1);
    const int z0 = min(max(iz,     0), GRID_RES - 1);
    const int z1 = min(max(iz + 1, 0), GRID_RES - 1);

    const int cx[2] = {x0, x1};
    const int cy[2] = {y0, y1};
    const int cz[2] = {z0, z1};
    const float fx[2] = {wax, wbx};
    const float fy[2] = {way, wby};
    const float fz[2] = {waz, wbz};

    fvec4 acc = (fvec4)(0.0f);

    // corner order matches reference _OFFSETS: (x,y,z) = 000,001,010,011,100,...
    #pragma unroll
    for (int ox = 0; ox < 2; ++ox) {
        #pragma unroll
        for (int oy = 0; oy < 2; ++oy) {
            #pragma unroll
            for (int oz = 0; oz < 2; ++oz) {
                const int flat = cx[ox] * (GRID_RES * GRID_RES)
                               + cy[oy] * GRID_RES + cz[oz];
                const float w = fx[ox] * fy[oy] * fz[oz];
                const fvec4 f = *reinterpret_cast<const fvec4*>(
                    latents + (size_t)flat * LATENT_DIM + q * 4);
                acc += w * f;
            }
        }
    }

    __builtin_nontemporal_store(acc,
        reinterpret_cast<fvec4*>(out + (size_t)p * LATENT_DIM + q * 4));
}

extern "C" void kernel_launch(void* const* d_in, const int* in_sizes, int n_in,
                              void* d_out, int out_size, void* d_ws, size_t ws_size,
                              hipStream_t stream) {
    const float* pts     = (const float*)d_in[0];
    const float* latents = (const float*)d_in[1];
    float* out = (float*)d_out;

    const int n_pts = in_sizes[0] / 3;
    const int total_threads = n_pts * 4;
    const int block = 256;
    const int grid = (total_threads + block - 1) / block;

    trilerp_kernel<<<grid, block, 0, stream>>>(pts, latents, out, n_pts);
}